// Round 3
// baseline (1223.817 us; speedup 1.0000x reference)
//
#include <hip/hip_runtime.h>
#include <hip/hip_bf16.h>
#include <math.h>

// ---------------------------------------------------------------------------
// DGSR layer, MI355X. H = 128 fixed.
//   1. CSR build: histogram -> 3-kernel scan -> edge-id scatter
//   2. 6 projections (f32 register-tiled GEMM)
//   3. edge_dots: coalesced pass over pVui/pKiu computing all 4 exp(logit)
//      scalars per edge (no max-subtraction: logits ~N(0,1.4))
//   4. gather_u / gather_i: one wave per segment, 2 edges/iter (half-wave
//      float4), accumulate numerators + denominators in registers, divide.
// No f32 atomics; pVui/pKiu each streamed exactly twice (minimum).
// ---------------------------------------------------------------------------

#define WB 1024  // elements per scan block

// ----------------------- GEMM: O[r][c] = sum_k X[g(r)][k] * W[c][k] --------
__global__ __launch_bounds__(256) void gemm_xwt_kernel(
    const float* __restrict__ X, const float* __restrict__ W,
    float* __restrict__ O, const int* __restrict__ gidx, int nrows)
{
    __shared__ float Xl[64 * 32];
    __shared__ float Wl[128 * 32];
    const int t  = threadIdx.x;
    const int tx = t & 15;
    const int ty = t >> 4;
    const int brow = blockIdx.x * 64;

    float acc[4][8];
#pragma unroll
    for (int j = 0; j < 4; ++j)
#pragma unroll
        for (int i = 0; i < 8; ++i) acc[j][i] = 0.f;

    for (int k0 = 0; k0 < 128; k0 += 32) {
        __syncthreads();
#pragma unroll
        for (int u = 0; u < 2; ++u) {
            int idx4 = t + u * 256;
            int r  = idx4 >> 3;
            int k4 = idx4 & 7;
            int row = brow + r;
            float4 v = make_float4(0.f, 0.f, 0.f, 0.f);
            if (row < nrows) {
                int g = gidx ? gidx[row] : row;
                v = *(const float4*)(X + (size_t)g * 128 + k0 + k4 * 4);
            }
            int sw = k4 ^ ((r >> 3) & 7);
            *(float4*)(Xl + r * 32 + sw * 4) = v;
        }
#pragma unroll
        for (int u = 0; u < 4; ++u) {
            int idx4 = t + u * 256;
            int c  = idx4 >> 3;
            int k4 = idx4 & 7;
            float4 v = *(const float4*)(W + (size_t)c * 128 + k0 + k4 * 4);
            int sw = k4 ^ ((c >> 3) & 7);
            *(float4*)(Wl + c * 32 + sw * 4) = v;
        }
        __syncthreads();
#pragma unroll
        for (int k4 = 0; k4 < 8; ++k4) {
            float4 xv[4], wv[8];
#pragma unroll
            for (int j = 0; j < 4; ++j) {
                int r = ty * 4 + j;
                xv[j] = *(const float4*)(Xl + r * 32 + ((k4 ^ ((r >> 3) & 7)) * 4));
            }
#pragma unroll
            for (int i = 0; i < 8; ++i) {
                int c = tx * 8 + i;
                wv[i] = *(const float4*)(Wl + c * 32 + ((k4 ^ ((c >> 3) & 7)) * 4));
            }
#pragma unroll
            for (int j = 0; j < 4; ++j)
#pragma unroll
                for (int i = 0; i < 8; ++i) {
                    acc[j][i] += xv[j].x * wv[i].x;
                    acc[j][i] += xv[j].y * wv[i].y;
                    acc[j][i] += xv[j].z * wv[i].z;
                    acc[j][i] += xv[j].w * wv[i].w;
                }
        }
    }
#pragma unroll
    for (int j = 0; j < 4; ++j) {
        int row = brow + ty * 4 + j;
        if (row < nrows) {
            float* op = O + (size_t)row * 128 + tx * 8;
            *(float4*)(op)     = make_float4(acc[j][0], acc[j][1], acc[j][2], acc[j][3]);
            *(float4*)(op + 4) = make_float4(acc[j][4], acc[j][5], acc[j][6], acc[j][7]);
        }
    }
}

// ----------------------- CSR build ------------------------------------------
__global__ __launch_bounds__(256) void hist_kernel(
    const int* __restrict__ ei, int E,
    int* __restrict__ deg_u, int* __restrict__ deg_i)
{
    int e = blockIdx.x * 256 + threadIdx.x;
    if (e < E) {
        atomicAdd(&deg_u[ei[e]], 1);
        atomicAdd(&deg_i[ei[E + e]], 1);
    }
}

__global__ __launch_bounds__(256) void scan_blocksums_kernel(
    const int* __restrict__ deg_u, int nu, int nbu,
    const int* __restrict__ deg_i, int ni,
    int* __restrict__ bsum)
{
    int b = blockIdx.x;
    const int* deg; int n; int base;
    if (b < nbu) { deg = deg_u; n = nu; base = b * WB; }
    else         { deg = deg_i; n = ni; base = (b - nbu) * WB; }
    int t = threadIdx.x;
    int s = 0;
#pragma unroll
    for (int j = 0; j < 4; ++j) {
        int i = base + t * 4 + j;
        if (i < n) s += deg[i];
    }
#pragma unroll
    for (int o = 32; o > 0; o >>= 1) s += __shfl_xor(s, o);
    __shared__ int wt[4];
    if ((t & 63) == 0) wt[t >> 6] = s;
    __syncthreads();
    if (t == 0) bsum[b] = wt[0] + wt[1] + wt[2] + wt[3];
}

__global__ void scan_partials_kernel(
    const int* __restrict__ bsum, int* __restrict__ bscan,
    int nbu, int nbi,
    int* __restrict__ off_u, int nu, int* __restrict__ off_i, int ni)
{
    if (threadIdx.x != 0) return;
    if (blockIdx.x == 0) {
        int c = 0;
        for (int b = 0; b < nbu; ++b) { bscan[b] = c; c += bsum[b]; }
        off_u[nu] = c;
    } else {
        int c = 0;
        for (int b = 0; b < nbi; ++b) { bscan[nbu + b] = c; c += bsum[nbu + b]; }
        off_i[ni] = c;
    }
}

__global__ __launch_bounds__(256) void scan_final_kernel(
    const int* __restrict__ deg_u, int nu, int nbu,
    const int* __restrict__ deg_i, int ni,
    const int* __restrict__ bscan,
    int* __restrict__ off_u, int* __restrict__ cur_u,
    int* __restrict__ off_i, int* __restrict__ cur_i)
{
    int b = blockIdx.x;
    const int* deg; int n; int base; int* off; int* cur;
    if (b < nbu) { deg = deg_u; n = nu; base = b * WB; off = off_u; cur = cur_u; }
    else         { deg = deg_i; n = ni; base = (b - nbu) * WB; off = off_i; cur = cur_i; }
    int t = threadIdx.x;
    int lane = t & 63, w = t >> 6;
    int v[4];
    int s = 0;
#pragma unroll
    for (int j = 0; j < 4; ++j) {
        int i = base + t * 4 + j;
        v[j] = (i < n) ? deg[i] : 0;
        s += v[j];
    }
    int inc = s;
#pragma unroll
    for (int o = 1; o < 64; o <<= 1) {
        int x = __shfl_up(inc, o);
        if (lane >= o) inc += x;
    }
    int excl = inc - s;
    __shared__ int wt[4];
    if (lane == 63) wt[w] = inc;
    __syncthreads();
    int wbase = 0;
    for (int j = 0; j < w; ++j) wbase += wt[j];
    int e = bscan[b] + wbase + excl;
#pragma unroll
    for (int j = 0; j < 4; ++j) {
        int i = base + t * 4 + j;
        if (i < n) { off[i] = e; cur[i] = e; }
        e += v[j];
    }
}

__global__ __launch_bounds__(256) void scatter_ids_kernel(
    const int* __restrict__ ei, int E,
    int* __restrict__ cur_u, int* __restrict__ cur_i,
    int* __restrict__ eu_list, int* __restrict__ ei_list)
{
    int e = blockIdx.x * 256 + threadIdx.x;
    if (e < E) {
        int pu = atomicAdd(&cur_u[ei[e]], 1);
        eu_list[pu] = e;
        int pi = atomicAdd(&cur_i[ei[E + e]], 1);
        ei_list[pi] = e;
    }
}

// ----------------------- Edge dots (coalesced, 2 edges/wave) ----------------
__global__ __launch_bounds__(256) void edge_dots_kernel(
    const float* __restrict__ um_att, const float* __restrict__ im_att,
    const float* __restrict__ last_item, const float* __restrict__ last_user,
    const float* __restrict__ pVui, const float* __restrict__ pKiu,
    const int* __restrict__ ei, int E,
    float* __restrict__ x1, float* __restrict__ x2,
    float* __restrict__ x3, float* __restrict__ x4, float inv_sqrt_d)
{
    const size_t tid = (size_t)blockIdx.x * blockDim.x + threadIdx.x;
    const int wav  = (int)(tid >> 6);
    const int lane = threadIdx.x & 63;
    const int hw = lane >> 5, hl = lane & 31;
    const int e = wav * 2 + hw;
    if (e >= E) return;
    const int src = ei[e], dst = ei[E + e];
    float4 um = ((const float4*)(um_att    + (size_t)src * 128))[hl];
    float4 im = ((const float4*)(im_att    + (size_t)dst * 128))[hl];
    float4 li = ((const float4*)(last_item + (size_t)src * 128))[hl];
    float4 lu = ((const float4*)(last_user + (size_t)src * 128))[hl];
    float4 pv = ((const float4*)(pVui      + (size_t)e   * 128))[hl];
    float4 pk = ((const float4*)(pKiu      + (size_t)e   * 128))[hl];

    float d0 = um.x*im.x + um.y*im.y + um.z*im.z + um.w*im.w;
    float d1 = um.x*pv.x + um.y*pv.y + um.z*pv.z + um.w*pv.w;
    float d2 = im.x*pk.x + im.y*pk.y + im.z*pk.z + im.w*pk.w;
    float d3 = li.x*im.x + li.y*im.y + li.z*im.z + li.w*im.w;
    float d4 = lu.x*im.x + lu.y*im.y + lu.z*im.z + lu.w*im.w;
#pragma unroll
    for (int o = 16; o > 0; o >>= 1) {
        d0 += __shfl_xor(d0, o);
        d1 += __shfl_xor(d1, o);
        d2 += __shfl_xor(d2, o);
        d3 += __shfl_xor(d3, o);
        d4 += __shfl_xor(d4, o);
    }
    if (hl == 0) {
        x1[e] = __expf((d0 + d1) * inv_sqrt_d);
        x2[e] = __expf((d0 + d2) * inv_sqrt_d);
        x3[e] = __expf(d3 * inv_sqrt_d);
        x4[e] = __expf(d4 * inv_sqrt_d);
    }
}

// ----------------------- Gather passes (2 edges/iter) -----------------------
__global__ __launch_bounds__(256) void gather_u_kernel(
    const float* __restrict__ im_att, const float* __restrict__ im_b,
    const float* __restrict__ pKiu,
    const int* __restrict__ ei, int E,
    const int* __restrict__ off_u, const int* __restrict__ eu_list,
    const float* __restrict__ x1, const float* __restrict__ x3,
    float* __restrict__ hLu, float* __restrict__ hSu, int U)
{
    const int wid  = (int)(((size_t)blockIdx.x * blockDim.x + threadIdx.x) >> 6);
    const int lane = threadIdx.x & 63;
    if (wid >= U) return;
    const int hw = lane >> 5, hl = lane & 31;

    float4 a1 = make_float4(0.f,0.f,0.f,0.f), a3 = make_float4(0.f,0.f,0.f,0.f);
    float s1 = 0.f, s3 = 0.f;
    const int e0 = off_u[wid], e1 = off_u[wid + 1];
    for (int e = e0 + hw; e < e1; e += 2) {
        int eid = eu_list[e];
        int dst = ei[E + eid];
        float xv1 = x1[eid], xv3 = x3[eid];
        float4 ib = ((const float4*)(im_b   + (size_t)dst * 128))[hl];
        float4 pk = ((const float4*)(pKiu   + (size_t)eid * 128))[hl];
        float4 ia = ((const float4*)(im_att + (size_t)dst * 128))[hl];
        a1.x += xv1*(ib.x+pk.x); a1.y += xv1*(ib.y+pk.y);
        a1.z += xv1*(ib.z+pk.z); a1.w += xv1*(ib.w+pk.w);
        a3.x += xv3*(ia.x+1.f);  a3.y += xv3*(ia.y+1.f);
        a3.z += xv3*(ia.z+1.f);  a3.w += xv3*(ia.w+1.f);
        s1 += xv1; s3 += xv3;
    }
    a1.x += __shfl_xor(a1.x, 32); a1.y += __shfl_xor(a1.y, 32);
    a1.z += __shfl_xor(a1.z, 32); a1.w += __shfl_xor(a1.w, 32);
    a3.x += __shfl_xor(a3.x, 32); a3.y += __shfl_xor(a3.y, 32);
    a3.z += __shfl_xor(a3.z, 32); a3.w += __shfl_xor(a3.w, 32);
    s1 += __shfl_xor(s1, 32);     s3 += __shfl_xor(s3, 32);
    if (hw == 0) {
        float r1 = (s1 > 0.f) ? 1.f / s1 : 0.f;
        float r3 = (s3 > 0.f) ? 1.f / s3 : 0.f;
        ((float4*)(hLu + (size_t)wid * 128))[hl] =
            make_float4(a1.x*r1, a1.y*r1, a1.z*r1, a1.w*r1);
        ((float4*)(hSu + (size_t)wid * 128))[hl] =
            make_float4(a3.x*r3, a3.y*r3, a3.z*r3, a3.w*r3);
    }
}

__global__ __launch_bounds__(256) void gather_i_kernel(
    const float* __restrict__ um_att, const float* __restrict__ um_b,
    const float* __restrict__ pVui,
    const int* __restrict__ ei, int E,
    const int* __restrict__ off_i, const int* __restrict__ ei_list,
    const float* __restrict__ x2, const float* __restrict__ x4,
    float* __restrict__ hLi, float* __restrict__ hSi, int I)
{
    const int wid  = (int)(((size_t)blockIdx.x * blockDim.x + threadIdx.x) >> 6);
    const int lane = threadIdx.x & 63;
    if (wid >= I) return;
    const int hw = lane >> 5, hl = lane & 31;

    float4 a2 = make_float4(0.f,0.f,0.f,0.f), a4 = make_float4(0.f,0.f,0.f,0.f);
    float s2 = 0.f, s4 = 0.f;
    const int e0 = off_i[wid], e1 = off_i[wid + 1];
    for (int e = e0 + hw; e < e1; e += 2) {
        int eid = ei_list[e];
        int src = ei[eid];
        float xv2 = x2[eid], xv4 = x4[eid];
        float4 ub = ((const float4*)(um_b   + (size_t)src * 128))[hl];
        float4 pv = ((const float4*)(pVui   + (size_t)eid * 128))[hl];
        float4 ua = ((const float4*)(um_att + (size_t)src * 128))[hl];
        a2.x += xv2*(ub.x+pv.x); a2.y += xv2*(ub.y+pv.y);
        a2.z += xv2*(ub.z+pv.z); a2.w += xv2*(ub.w+pv.w);
        a4.x += xv4*(ua.x+1.f);  a4.y += xv4*(ua.y+1.f);
        a4.z += xv4*(ua.z+1.f);  a4.w += xv4*(ua.w+1.f);
        s2 += xv2; s4 += xv4;
    }
    a2.x += __shfl_xor(a2.x, 32); a2.y += __shfl_xor(a2.y, 32);
    a2.z += __shfl_xor(a2.z, 32); a2.w += __shfl_xor(a2.w, 32);
    a4.x += __shfl_xor(a4.x, 32); a4.y += __shfl_xor(a4.y, 32);
    a4.z += __shfl_xor(a4.z, 32); a4.w += __shfl_xor(a4.w, 32);
    s2 += __shfl_xor(s2, 32);     s4 += __shfl_xor(s4, 32);
    if (hw == 0) {
        float r2 = (s2 > 0.f) ? 1.f / s2 : 0.f;
        float r4 = (s4 > 0.f) ? 1.f / s4 : 0.f;
        ((float4*)(hLi + (size_t)wid * 128))[hl] =
            make_float4(a2.x*r2, a2.y*r2, a2.z*r2, a2.w*r2);
        ((float4*)(hSi + (size_t)wid * 128))[hl] =
            make_float4(a4.x*r4, a4.y*r4, a4.z*r4, a4.w*r4);
    }
}

// ---------------------------------------------------------------------------
extern "C" void kernel_launch(void* const* d_in, const int* in_sizes, int n_in,
                              void* d_out, int out_size, void* d_ws, size_t ws_size,
                              hipStream_t stream)
{
    const float* u_emb = (const float*)d_in[0];
    const float* i_emb = (const float*)d_in[1];
    const float* pVui  = (const float*)d_in[2];
    const float* pKiu  = (const float*)d_in[3];
    const float* w1    = (const float*)d_in[4];
    const float* w2    = (const float*)d_in[5];
    const float* w1b   = (const float*)d_in[6];
    const float* w2b   = (const float*)d_in[7];
    const float* w3    = (const float*)d_in[8];
    const float* w4    = (const float*)d_in[9];
    const int* edge_index = (const int*)d_in[10];
    const int* last_u     = (const int*)d_in[11];
    const int* last_i     = (const int*)d_in[12];

    const int U = in_sizes[0] / 128;
    const int I = in_sizes[1] / 128;
    const int E = in_sizes[10] / 2;
    const int nbu = (U + WB - 1) / WB;
    const int nbi = (I + WB - 1) / WB;

    float* ws = (float*)d_ws;
    float* um_att    = ws;  ws += (size_t)U * 128;
    float* im_att    = ws;  ws += (size_t)I * 128;
    float* um_b      = ws;  ws += (size_t)U * 128;
    float* im_b      = ws;  ws += (size_t)I * 128;
    float* last_item = ws;  ws += (size_t)U * 128;
    float* last_user = ws;  ws += (size_t)I * 128;
    float* x1 = ws;  ws += E;
    float* x2 = ws;  ws += E;
    float* x3 = ws;  ws += E;
    float* x4 = ws;  ws += E;
    int* ip = (int*)ws;
    int* deg_u   = ip;  ip += U;
    int* deg_i   = ip;  ip += I;
    int* off_u   = ip;  ip += U + 1;
    int* off_i   = ip;  ip += I + 1;
    int* cur_u   = ip;  ip += U;
    int* cur_i   = ip;  ip += I;
    int* eu_list = ip;  ip += E;
    int* ei_list = ip;  ip += E;
    int* bsum    = ip;  ip += nbu + nbi;
    int* bscan   = ip;  ip += nbu + nbi;

    float* hLu = (float*)d_out;
    float* hSu = hLu + (size_t)U * 128;
    float* hLi = hSu + (size_t)U * 128;
    float* hSi = hLi + (size_t)I * 128;

    hipMemsetAsync(deg_u, 0, (size_t)(U + I) * sizeof(int), stream);

    dim3 blk(256);
    const int eblk = (E + 255) / 256;
    hist_kernel<<<eblk, blk, 0, stream>>>(edge_index, E, deg_u, deg_i);
    scan_blocksums_kernel<<<nbu + nbi, blk, 0, stream>>>(deg_u, U, nbu, deg_i, I, bsum);
    scan_partials_kernel<<<2, 64, 0, stream>>>(bsum, bscan, nbu, nbi, off_u, U, off_i, I);
    scan_final_kernel<<<nbu + nbi, blk, 0, stream>>>(
        deg_u, U, nbu, deg_i, I, bscan, off_u, cur_u, off_i, cur_i);
    scatter_ids_kernel<<<eblk, blk, 0, stream>>>(edge_index, E, cur_u, cur_i, eu_list, ei_list);

    gemm_xwt_kernel<<<(U + 63) / 64, blk, 0, stream>>>(u_emb, w2,  um_att,    nullptr,    U);
    gemm_xwt_kernel<<<(I + 63) / 64, blk, 0, stream>>>(i_emb, w1,  im_att,    nullptr,    I);
    gemm_xwt_kernel<<<(U + 63) / 64, blk, 0, stream>>>(u_emb, w2b, um_b,      nullptr,    U);
    gemm_xwt_kernel<<<(I + 63) / 64, blk, 0, stream>>>(i_emb, w1b, im_b,      nullptr,    I);
    gemm_xwt_kernel<<<(U + 63) / 64, blk, 0, stream>>>(i_emb, w3,  last_item, last_u + U, U);
    gemm_xwt_kernel<<<(I + 63) / 64, blk, 0, stream>>>(u_emb, w4,  last_user, last_i + I, I);

    const float inv_sqrt_d = 1.0f / sqrtf(128.0f);
    edge_dots_kernel<<<(E + 7) / 8, blk, 0, stream>>>(
        um_att, im_att, last_item, last_user, pVui, pKiu, edge_index, E,
        x1, x2, x3, x4, inv_sqrt_d);
    gather_u_kernel<<<(U + 3) / 4, blk, 0, stream>>>(
        im_att, im_b, pKiu, edge_index, E, off_u, eu_list, x1, x3, hLu, hSu, U);
    gather_i_kernel<<<(I + 3) / 4, blk, 0, stream>>>(
        um_att, um_b, pVui, edge_index, E, off_i, ei_list, x2, x4, hLi, hSi, I);
}

// Round 4
// 938.697 us; speedup vs baseline: 1.3037x; 1.3037x over previous
//
#include <hip/hip_runtime.h>
#include <hip/hip_bf16.h>
#include <math.h>

// ---------------------------------------------------------------------------
// DGSR layer, MI355X. H = 128 fixed.
//   1. CSR build: histogram -> 3-kernel scan -> edge-id scatter
//   2. 6 projections (f32 register-tiled GEMM, output stride param) into
//      fusedU=[um_att|um_b] ([U,256]), fusedI=[im_att|im_b] ([I,256]),
//      last_item, last_user
//   3. gather_u: one wave per user, 2 edges/iter (half-wave float4).
//      Computes ALL FIVE logit dots (user+item side), accumulates hLu/hSu
//      numerators+denominators in regs, writes x24[eid]={x2,x4} (8B/edge).
//   4. gather_i: pure streaming accumulate (no dots/shuffles): reads x24,
//      pVui (value), fusedU rows; accumulates hLi/hSi.
// pKiu read ONCE total; pVui twice. No f32 atomics anywhere.
// exp without max-subtraction: logits ~N(0,1.4), |logit| < ~9 -> safe in f32.
// ---------------------------------------------------------------------------

#define WB 1024  // elements per scan block

__device__ __forceinline__ float dot4(float4 a, float4 b) {
    return a.x * b.x + a.y * b.y + a.z * b.z + a.w * b.w;
}

// ----------------------- GEMM: O[r][c] = sum_k X[g(r)][k] * W[c][k] --------
__global__ __launch_bounds__(256) void gemm_xwt_kernel(
    const float* __restrict__ X, const float* __restrict__ W,
    float* __restrict__ O, int ostride, const int* __restrict__ gidx, int nrows)
{
    __shared__ float Xl[64 * 32];
    __shared__ float Wl[128 * 32];
    const int t  = threadIdx.x;
    const int tx = t & 15;
    const int ty = t >> 4;
    const int brow = blockIdx.x * 64;

    float acc[4][8];
#pragma unroll
    for (int j = 0; j < 4; ++j)
#pragma unroll
        for (int i = 0; i < 8; ++i) acc[j][i] = 0.f;

    for (int k0 = 0; k0 < 128; k0 += 32) {
        __syncthreads();
#pragma unroll
        for (int u = 0; u < 2; ++u) {
            int idx4 = t + u * 256;
            int r  = idx4 >> 3;
            int k4 = idx4 & 7;
            int row = brow + r;
            float4 v = make_float4(0.f, 0.f, 0.f, 0.f);
            if (row < nrows) {
                int g = gidx ? gidx[row] : row;
                v = *(const float4*)(X + (size_t)g * 128 + k0 + k4 * 4);
            }
            int sw = k4 ^ ((r >> 3) & 7);
            *(float4*)(Xl + r * 32 + sw * 4) = v;
        }
#pragma unroll
        for (int u = 0; u < 4; ++u) {
            int idx4 = t + u * 256;
            int c  = idx4 >> 3;
            int k4 = idx4 & 7;
            float4 v = *(const float4*)(W + (size_t)c * 128 + k0 + k4 * 4);
            int sw = k4 ^ ((c >> 3) & 7);
            *(float4*)(Wl + c * 32 + sw * 4) = v;
        }
        __syncthreads();
#pragma unroll
        for (int k4 = 0; k4 < 8; ++k4) {
            float4 xv[4], wv[8];
#pragma unroll
            for (int j = 0; j < 4; ++j) {
                int r = ty * 4 + j;
                xv[j] = *(const float4*)(Xl + r * 32 + ((k4 ^ ((r >> 3) & 7)) * 4));
            }
#pragma unroll
            for (int i = 0; i < 8; ++i) {
                int c = tx * 8 + i;
                wv[i] = *(const float4*)(Wl + c * 32 + ((k4 ^ ((c >> 3) & 7)) * 4));
            }
#pragma unroll
            for (int j = 0; j < 4; ++j)
#pragma unroll
                for (int i = 0; i < 8; ++i) {
                    acc[j][i] += xv[j].x * wv[i].x;
                    acc[j][i] += xv[j].y * wv[i].y;
                    acc[j][i] += xv[j].z * wv[i].z;
                    acc[j][i] += xv[j].w * wv[i].w;
                }
        }
    }
#pragma unroll
    for (int j = 0; j < 4; ++j) {
        int row = brow + ty * 4 + j;
        if (row < nrows) {
            float* op = O + (size_t)row * ostride + tx * 8;
            *(float4*)(op)     = make_float4(acc[j][0], acc[j][1], acc[j][2], acc[j][3]);
            *(float4*)(op + 4) = make_float4(acc[j][4], acc[j][5], acc[j][6], acc[j][7]);
        }
    }
}

// ----------------------- CSR build ------------------------------------------
__global__ __launch_bounds__(256) void hist_kernel(
    const int* __restrict__ ei, int E,
    int* __restrict__ deg_u, int* __restrict__ deg_i)
{
    int e = blockIdx.x * 256 + threadIdx.x;
    if (e < E) {
        atomicAdd(&deg_u[ei[e]], 1);
        atomicAdd(&deg_i[ei[E + e]], 1);
    }
}

__global__ __launch_bounds__(256) void scan_blocksums_kernel(
    const int* __restrict__ deg_u, int nu, int nbu,
    const int* __restrict__ deg_i, int ni,
    int* __restrict__ bsum)
{
    int b = blockIdx.x;
    const int* deg; int n; int base;
    if (b < nbu) { deg = deg_u; n = nu; base = b * WB; }
    else         { deg = deg_i; n = ni; base = (b - nbu) * WB; }
    int t = threadIdx.x;
    int s = 0;
#pragma unroll
    for (int j = 0; j < 4; ++j) {
        int i = base + t * 4 + j;
        if (i < n) s += deg[i];
    }
#pragma unroll
    for (int o = 32; o > 0; o >>= 1) s += __shfl_xor(s, o);
    __shared__ int wt[4];
    if ((t & 63) == 0) wt[t >> 6] = s;
    __syncthreads();
    if (t == 0) bsum[b] = wt[0] + wt[1] + wt[2] + wt[3];
}

__global__ void scan_partials_kernel(
    const int* __restrict__ bsum, int* __restrict__ bscan,
    int nbu, int nbi,
    int* __restrict__ off_u, int nu, int* __restrict__ off_i, int ni)
{
    if (threadIdx.x != 0) return;
    if (blockIdx.x == 0) {
        int c = 0;
        for (int b = 0; b < nbu; ++b) { bscan[b] = c; c += bsum[b]; }
        off_u[nu] = c;
    } else {
        int c = 0;
        for (int b = 0; b < nbi; ++b) { bscan[nbu + b] = c; c += bsum[nbu + b]; }
        off_i[ni] = c;
    }
}

__global__ __launch_bounds__(256) void scan_final_kernel(
    const int* __restrict__ deg_u, int nu, int nbu,
    const int* __restrict__ deg_i, int ni,
    const int* __restrict__ bscan,
    int* __restrict__ off_u, int* __restrict__ cur_u,
    int* __restrict__ off_i, int* __restrict__ cur_i)
{
    int b = blockIdx.x;
    const int* deg; int n; int base; int* off; int* cur;
    if (b < nbu) { deg = deg_u; n = nu; base = b * WB; off = off_u; cur = cur_u; }
    else         { deg = deg_i; n = ni; base = (b - nbu) * WB; off = off_i; cur = cur_i; }
    int t = threadIdx.x;
    int lane = t & 63, w = t >> 6;
    int v[4];
    int s = 0;
#pragma unroll
    for (int j = 0; j < 4; ++j) {
        int i = base + t * 4 + j;
        v[j] = (i < n) ? deg[i] : 0;
        s += v[j];
    }
    int inc = s;
#pragma unroll
    for (int o = 1; o < 64; o <<= 1) {
        int x = __shfl_up(inc, o);
        if (lane >= o) inc += x;
    }
    int excl = inc - s;
    __shared__ int wt[4];
    if (lane == 63) wt[w] = inc;
    __syncthreads();
    int wbase = 0;
    for (int j = 0; j < w; ++j) wbase += wt[j];
    int e = bscan[b] + wbase + excl;
#pragma unroll
    for (int j = 0; j < 4; ++j) {
        int i = base + t * 4 + j;
        if (i < n) { off[i] = e; cur[i] = e; }
        e += v[j];
    }
}

__global__ __launch_bounds__(256) void scatter_ids_kernel(
    const int* __restrict__ ei, int E,
    int* __restrict__ cur_u, int* __restrict__ cur_i,
    int* __restrict__ eu_list, int* __restrict__ ei_list)
{
    int e = blockIdx.x * 256 + threadIdx.x;
    if (e < E) {
        int pu = atomicAdd(&cur_u[ei[e]], 1);
        eu_list[pu] = e;
        int pi = atomicAdd(&cur_i[ei[E + e]], 1);
        ei_list[pi] = e;
    }
}

// ----------------------- gather_u: all dots + user-side outputs -------------
__global__ __launch_bounds__(256) void gather_u_kernel(
    const float* __restrict__ fusedU,   // [U,256]: um_att | um_b
    const float* __restrict__ fusedI,   // [I,256]: im_att | im_b
    const float* __restrict__ last_item, const float* __restrict__ last_user,
    const float* __restrict__ pVui, const float* __restrict__ pKiu,
    const int* __restrict__ ei, int E,
    const int* __restrict__ off_u, const int* __restrict__ eu_list,
    float2* __restrict__ x24,
    float* __restrict__ hLu, float* __restrict__ hSu, int U, float inv_sqrt_d)
{
    const int wid  = (int)(((size_t)blockIdx.x * blockDim.x + threadIdx.x) >> 6);
    const int lane = threadIdx.x & 63;
    if (wid >= U) return;
    const int hw = lane >> 5, hl = lane & 31;

    const float4 um = ((const float4*)(fusedU    + (size_t)wid * 256))[hl];
    const float4 li = ((const float4*)(last_item + (size_t)wid * 128))[hl];
    const float4 lu = ((const float4*)(last_user + (size_t)wid * 128))[hl];

    float4 a1 = make_float4(0.f,0.f,0.f,0.f), a3 = make_float4(0.f,0.f,0.f,0.f);
    float s1 = 0.f, s3 = 0.f;
    const int e0 = off_u[wid], e1 = off_u[wid + 1];
    for (int e = e0 + hw; e < e1; e += 2) {
        const int eid = eu_list[e];
        const int dst = ei[E + eid];
        const float* fI = fusedI + (size_t)dst * 256;
        float4 ia = ((const float4*)fI)[hl];
        float4 ib = ((const float4*)fI)[hl + 32];
        float4 pv = ((const float4*)(pVui + (size_t)eid * 128))[hl];
        float4 pk = ((const float4*)(pKiu + (size_t)eid * 128))[hl];

        float d0 = dot4(um, ia);
        float d1 = dot4(um, pv);
        float d2 = dot4(ia, pk);
        float d3 = dot4(li, ia);
        float d4 = dot4(lu, ia);
#pragma unroll
        for (int o = 16; o > 0; o >>= 1) {
            d0 += __shfl_xor(d0, o);
            d1 += __shfl_xor(d1, o);
            d2 += __shfl_xor(d2, o);
            d3 += __shfl_xor(d3, o);
            d4 += __shfl_xor(d4, o);
        }
        float x1 = __expf((d0 + d1) * inv_sqrt_d);
        float x2 = __expf((d0 + d2) * inv_sqrt_d);
        float x3 = __expf(d3 * inv_sqrt_d);
        float x4 = __expf(d4 * inv_sqrt_d);
        a1.x += x1*(ib.x+pk.x); a1.y += x1*(ib.y+pk.y);
        a1.z += x1*(ib.z+pk.z); a1.w += x1*(ib.w+pk.w);
        a3.x += x3*(ia.x+1.f);  a3.y += x3*(ia.y+1.f);
        a3.z += x3*(ia.z+1.f);  a3.w += x3*(ia.w+1.f);
        s1 += x1; s3 += x3;
        if (hl == 0) x24[eid] = make_float2(x2, x4);
    }
    a1.x += __shfl_xor(a1.x, 32); a1.y += __shfl_xor(a1.y, 32);
    a1.z += __shfl_xor(a1.z, 32); a1.w += __shfl_xor(a1.w, 32);
    a3.x += __shfl_xor(a3.x, 32); a3.y += __shfl_xor(a3.y, 32);
    a3.z += __shfl_xor(a3.z, 32); a3.w += __shfl_xor(a3.w, 32);
    s1 += __shfl_xor(s1, 32);     s3 += __shfl_xor(s3, 32);
    if (hw == 0) {
        float r1 = (s1 > 0.f) ? 1.f / s1 : 0.f;
        float r3 = (s3 > 0.f) ? 1.f / s3 : 0.f;
        ((float4*)(hLu + (size_t)wid * 128))[hl] =
            make_float4(a1.x*r1, a1.y*r1, a1.z*r1, a1.w*r1);
        ((float4*)(hSu + (size_t)wid * 128))[hl] =
            make_float4(a3.x*r3, a3.y*r3, a3.z*r3, a3.w*r3);
    }
}

// ----------------------- gather_i: pure streaming accumulate ----------------
__global__ __launch_bounds__(256) void gather_i_kernel(
    const float* __restrict__ fusedU,   // [U,256]: um_att | um_b
    const float* __restrict__ pVui,
    const int* __restrict__ ei, int E,
    const int* __restrict__ off_i, const int* __restrict__ ei_list,
    const float2* __restrict__ x24,
    float* __restrict__ hLi, float* __restrict__ hSi, int I)
{
    const int wid  = (int)(((size_t)blockIdx.x * blockDim.x + threadIdx.x) >> 6);
    const int lane = threadIdx.x & 63;
    if (wid >= I) return;
    const int hw = lane >> 5, hl = lane & 31;

    float4 a2 = make_float4(0.f,0.f,0.f,0.f), a4 = make_float4(0.f,0.f,0.f,0.f);
    float s2 = 0.f, s4 = 0.f;
    const int e0 = off_i[wid], e1 = off_i[wid + 1];
    for (int e = e0 + hw; e < e1; e += 2) {
        const int eid = ei_list[e];
        const int src = ei[eid];
        const float2 x = x24[eid];
        const float* fU = fusedU + (size_t)src * 256;
        float4 ua = ((const float4*)fU)[hl];
        float4 ub = ((const float4*)fU)[hl + 32];
        float4 pv = ((const float4*)(pVui + (size_t)eid * 128))[hl];
        a2.x += x.x*(ub.x+pv.x); a2.y += x.x*(ub.y+pv.y);
        a2.z += x.x*(ub.z+pv.z); a2.w += x.x*(ub.w+pv.w);
        a4.x += x.y*(ua.x+1.f);  a4.y += x.y*(ua.y+1.f);
        a4.z += x.y*(ua.z+1.f);  a4.w += x.y*(ua.w+1.f);
        s2 += x.x; s4 += x.y;
    }
    a2.x += __shfl_xor(a2.x, 32); a2.y += __shfl_xor(a2.y, 32);
    a2.z += __shfl_xor(a2.z, 32); a2.w += __shfl_xor(a2.w, 32);
    a4.x += __shfl_xor(a4.x, 32); a4.y += __shfl_xor(a4.y, 32);
    a4.z += __shfl_xor(a4.w - a4.w + a4.z, 32); a4.w += __shfl_xor(a4.w, 32);
    s2 += __shfl_xor(s2, 32);     s4 += __shfl_xor(s4, 32);
    if (hw == 0) {
        float r2 = (s2 > 0.f) ? 1.f / s2 : 0.f;
        float r4 = (s4 > 0.f) ? 1.f / s4 : 0.f;
        ((float4*)(hLi + (size_t)wid * 128))[hl] =
            make_float4(a2.x*r2, a2.y*r2, a2.z*r2, a2.w*r2);
        ((float4*)(hSi + (size_t)wid * 128))[hl] =
            make_float4(a4.x*r4, a4.y*r4, a4.z*r4, a4.w*r4);
    }
}

// ---------------------------------------------------------------------------
extern "C" void kernel_launch(void* const* d_in, const int* in_sizes, int n_in,
                              void* d_out, int out_size, void* d_ws, size_t ws_size,
                              hipStream_t stream)
{
    const float* u_emb = (const float*)d_in[0];
    const float* i_emb = (const float*)d_in[1];
    const float* pVui  = (const float*)d_in[2];
    const float* pKiu  = (const float*)d_in[3];
    const float* w1    = (const float*)d_in[4];
    const float* w2    = (const float*)d_in[5];
    const float* w1b   = (const float*)d_in[6];
    const float* w2b   = (const float*)d_in[7];
    const float* w3    = (const float*)d_in[8];
    const float* w4    = (const float*)d_in[9];
    const int* edge_index = (const int*)d_in[10];
    const int* last_u     = (const int*)d_in[11];
    const int* last_i     = (const int*)d_in[12];

    const int U = in_sizes[0] / 128;
    const int I = in_sizes[1] / 128;
    const int E = in_sizes[10] / 2;
    const int nbu = (U + WB - 1) / WB;
    const int nbi = (I + WB - 1) / WB;

    float* ws = (float*)d_ws;
    float* fusedU    = ws;  ws += (size_t)U * 256;
    float* fusedI    = ws;  ws += (size_t)I * 256;
    float* last_item = ws;  ws += (size_t)U * 128;
    float* last_user = ws;  ws += (size_t)I * 128;
    float2* x24 = (float2*)ws;  ws += (size_t)E * 2;
    int* ip = (int*)ws;
    int* deg_u   = ip;  ip += U;
    int* deg_i   = ip;  ip += I;
    int* off_u   = ip;  ip += U + 1;
    int* off_i   = ip;  ip += I + 1;
    int* cur_u   = ip;  ip += U;
    int* cur_i   = ip;  ip += I;
    int* eu_list = ip;  ip += E;
    int* ei_list = ip;  ip += E;
    int* bsum    = ip;  ip += nbu + nbi;
    int* bscan   = ip;  ip += nbu + nbi;

    float* hLu = (float*)d_out;
    float* hSu = hLu + (size_t)U * 128;
    float* hLi = hSu + (size_t)U * 128;
    float* hSi = hLi + (size_t)I * 128;

    hipMemsetAsync(deg_u, 0, (size_t)(U + I) * sizeof(int), stream);

    dim3 blk(256);
    const int eblk = (E + 255) / 256;
    hist_kernel<<<eblk, blk, 0, stream>>>(edge_index, E, deg_u, deg_i);
    scan_blocksums_kernel<<<nbu + nbi, blk, 0, stream>>>(deg_u, U, nbu, deg_i, I, bsum);
    scan_partials_kernel<<<2, 64, 0, stream>>>(bsum, bscan, nbu, nbi, off_u, U, off_i, I);
    scan_final_kernel<<<nbu + nbi, blk, 0, stream>>>(
        deg_u, U, nbu, deg_i, I, bscan, off_u, cur_u, off_i, cur_i);
    scatter_ids_kernel<<<eblk, blk, 0, stream>>>(edge_index, E, cur_u, cur_i, eu_list, ei_list);

    gemm_xwt_kernel<<<(U + 63) / 64, blk, 0, stream>>>(u_emb, w2,  fusedU,       256, nullptr,    U);
    gemm_xwt_kernel<<<(U + 63) / 64, blk, 0, stream>>>(u_emb, w2b, fusedU + 128, 256, nullptr,    U);
    gemm_xwt_kernel<<<(I + 63) / 64, blk, 0, stream>>>(i_emb, w1,  fusedI,       256, nullptr,    I);
    gemm_xwt_kernel<<<(I + 63) / 64, blk, 0, stream>>>(i_emb, w1b, fusedI + 128, 256, nullptr,    I);
    gemm_xwt_kernel<<<(U + 63) / 64, blk, 0, stream>>>(i_emb, w3,  last_item,    128, last_u + U, U);
    gemm_xwt_kernel<<<(I + 63) / 64, blk, 0, stream>>>(u_emb, w4,  last_user,    128, last_i + I, I);

    const float inv_sqrt_d = 1.0f / sqrtf(128.0f);
    gather_u_kernel<<<(U + 3) / 4, blk, 0, stream>>>(
        fusedU, fusedI, last_item, last_user, pVui, pKiu, edge_index, E,
        off_u, eu_list, x24, hLu, hSu, U, inv_sqrt_d);
    gather_i_kernel<<<(I + 3) / 4, blk, 0, stream>>>(
        fusedU, pVui, edge_index, E, off_i, ei_list, x24, hLi, hSi, I);
}

// Round 5
// 859.488 us; speedup vs baseline: 1.4239x; 1.0922x over previous
//
#include <hip/hip_runtime.h>
#include <hip/hip_bf16.h>
#include <math.h>

// ---------------------------------------------------------------------------
// DGSR layer, MI355X. H = 128 fixed.
//   1. CSR build: histogram -> 3-kernel scan -> edge-id scatter
//   2. gemm6: single fused launch of all 6 projections into
//      fusedU=[um_att|um_b] ([U,256]), fusedI=[im_att|im_b] ([I,256]),
//      last_item, last_user
//   3. gather_u: one wave per user, QUARTER-WAVE (16 lanes) per edge ->
//      4 edges in flight. Computes all 5 logit dots with 4 combined
//      butterfly chains (4 stages), accumulates hLu/hSu, writes x24[eid].
//   4. gather_i: quarter-wave streaming accumulate (no dots).
// pKiu read once, pVui twice (floor). Nontemporal loads on p-streams keep
// L2 for the fused tables. exp without max-subtraction (logits ~N(0,1.4)).
// ---------------------------------------------------------------------------

#define WB 1024  // elements per scan block

typedef float fvec4 __attribute__((ext_vector_type(4)));

__device__ __forceinline__ float4 nt_load4(const float* p) {
    fvec4 v = __builtin_nontemporal_load((const fvec4*)p);
    return make_float4(v.x, v.y, v.z, v.w);
}
__device__ __forceinline__ float dot4(float4 a, float4 b) {
    return a.x * b.x + a.y * b.y + a.z * b.z + a.w * b.w;
}

// ----------------------- fused 6x GEMM: O[r][c] = sum_k X[g(r)][k]*W[c][k] --
struct Gemm6Desc {
    const float* X[6];
    const float* W[6];
    float*       O[6];
    const int*   g[6];
    int          ostride[6];
    int          nrows[6];
};

__global__ __launch_bounds__(256) void gemm6_kernel(Gemm6Desc d)
{
    __shared__ float Xl[64 * 32];
    __shared__ float Wl[128 * 32];
    const int j6 = blockIdx.y;
    const float* __restrict__ X = d.X[j6];
    const float* __restrict__ W = d.W[j6];
    float* __restrict__ O       = d.O[j6];
    const int* __restrict__ gidx = d.g[j6];
    const int ostride = d.ostride[j6];
    const int nrows   = d.nrows[j6];

    const int t  = threadIdx.x;
    const int tx = t & 15;
    const int ty = t >> 4;
    const int brow = blockIdx.x * 64;
    if (brow >= nrows) return;

    float acc[4][8];
#pragma unroll
    for (int j = 0; j < 4; ++j)
#pragma unroll
        for (int i = 0; i < 8; ++i) acc[j][i] = 0.f;

    for (int k0 = 0; k0 < 128; k0 += 32) {
        __syncthreads();
#pragma unroll
        for (int u = 0; u < 2; ++u) {
            int idx4 = t + u * 256;
            int r  = idx4 >> 3;
            int k4 = idx4 & 7;
            int row = brow + r;
            float4 v = make_float4(0.f, 0.f, 0.f, 0.f);
            if (row < nrows) {
                int g = gidx ? gidx[row] : row;
                v = *(const float4*)(X + (size_t)g * 128 + k0 + k4 * 4);
            }
            int sw = k4 ^ ((r >> 3) & 7);
            *(float4*)(Xl + r * 32 + sw * 4) = v;
        }
#pragma unroll
        for (int u = 0; u < 4; ++u) {
            int idx4 = t + u * 256;
            int c  = idx4 >> 3;
            int k4 = idx4 & 7;
            float4 v = *(const float4*)(W + (size_t)c * 128 + k0 + k4 * 4);
            int sw = k4 ^ ((c >> 3) & 7);
            *(float4*)(Wl + c * 32 + sw * 4) = v;
        }
        __syncthreads();
#pragma unroll
        for (int k4 = 0; k4 < 8; ++k4) {
            float4 xv[4], wv[8];
#pragma unroll
            for (int j = 0; j < 4; ++j) {
                int r = ty * 4 + j;
                xv[j] = *(const float4*)(Xl + r * 32 + ((k4 ^ ((r >> 3) & 7)) * 4));
            }
#pragma unroll
            for (int i = 0; i < 8; ++i) {
                int c = tx * 8 + i;
                wv[i] = *(const float4*)(Wl + c * 32 + ((k4 ^ ((c >> 3) & 7)) * 4));
            }
#pragma unroll
            for (int j = 0; j < 4; ++j)
#pragma unroll
                for (int i = 0; i < 8; ++i) {
                    acc[j][i] += xv[j].x * wv[i].x;
                    acc[j][i] += xv[j].y * wv[i].y;
                    acc[j][i] += xv[j].z * wv[i].z;
                    acc[j][i] += xv[j].w * wv[i].w;
                }
        }
    }
#pragma unroll
    for (int j = 0; j < 4; ++j) {
        int row = brow + ty * 4 + j;
        if (row < nrows) {
            float* op = O + (size_t)row * ostride + tx * 8;
            *(float4*)(op)     = make_float4(acc[j][0], acc[j][1], acc[j][2], acc[j][3]);
            *(float4*)(op + 4) = make_float4(acc[j][4], acc[j][5], acc[j][6], acc[j][7]);
        }
    }
}

// ----------------------- CSR build ------------------------------------------
__global__ __launch_bounds__(256) void hist_kernel(
    const int* __restrict__ ei, int E,
    int* __restrict__ deg_u, int* __restrict__ deg_i)
{
    int e = blockIdx.x * 256 + threadIdx.x;
    if (e < E) {
        atomicAdd(&deg_u[ei[e]], 1);
        atomicAdd(&deg_i[ei[E + e]], 1);
    }
}

__global__ __launch_bounds__(256) void scan_blocksums_kernel(
    const int* __restrict__ deg_u, int nu, int nbu,
    const int* __restrict__ deg_i, int ni,
    int* __restrict__ bsum)
{
    int b = blockIdx.x;
    const int* deg; int n; int base;
    if (b < nbu) { deg = deg_u; n = nu; base = b * WB; }
    else         { deg = deg_i; n = ni; base = (b - nbu) * WB; }
    int t = threadIdx.x;
    int s = 0;
#pragma unroll
    for (int j = 0; j < 4; ++j) {
        int i = base + t * 4 + j;
        if (i < n) s += deg[i];
    }
#pragma unroll
    for (int o = 32; o > 0; o >>= 1) s += __shfl_xor(s, o);
    __shared__ int wt[4];
    if ((t & 63) == 0) wt[t >> 6] = s;
    __syncthreads();
    if (t == 0) bsum[b] = wt[0] + wt[1] + wt[2] + wt[3];
}

__global__ void scan_partials_kernel(
    const int* __restrict__ bsum, int* __restrict__ bscan,
    int nbu, int nbi,
    int* __restrict__ off_u, int nu, int* __restrict__ off_i, int ni)
{
    if (threadIdx.x != 0) return;
    if (blockIdx.x == 0) {
        int c = 0;
        for (int b = 0; b < nbu; ++b) { bscan[b] = c; c += bsum[b]; }
        off_u[nu] = c;
    } else {
        int c = 0;
        for (int b = 0; b < nbi; ++b) { bscan[nbu + b] = c; c += bsum[nbu + b]; }
        off_i[ni] = c;
    }
}

__global__ __launch_bounds__(256) void scan_final_kernel(
    const int* __restrict__ deg_u, int nu, int nbu,
    const int* __restrict__ deg_i, int ni,
    const int* __restrict__ bscan,
    int* __restrict__ off_u, int* __restrict__ cur_u,
    int* __restrict__ off_i, int* __restrict__ cur_i)
{
    int b = blockIdx.x;
    const int* deg; int n; int base; int* off; int* cur;
    if (b < nbu) { deg = deg_u; n = nu; base = b * WB; off = off_u; cur = cur_u; }
    else         { deg = deg_i; n = ni; base = (b - nbu) * WB; off = off_i; cur = cur_i; }
    int t = threadIdx.x;
    int lane = t & 63, w = t >> 6;
    int v[4];
    int s = 0;
#pragma unroll
    for (int j = 0; j < 4; ++j) {
        int i = base + t * 4 + j;
        v[j] = (i < n) ? deg[i] : 0;
        s += v[j];
    }
    int inc = s;
#pragma unroll
    for (int o = 1; o < 64; o <<= 1) {
        int x = __shfl_up(inc, o);
        if (lane >= o) inc += x;
    }
    int excl = inc - s;
    __shared__ int wt[4];
    if (lane == 63) wt[w] = inc;
    __syncthreads();
    int wbase = 0;
    for (int j = 0; j < w; ++j) wbase += wt[j];
    int e = bscan[b] + wbase + excl;
#pragma unroll
    for (int j = 0; j < 4; ++j) {
        int i = base + t * 4 + j;
        if (i < n) { off[i] = e; cur[i] = e; }
        e += v[j];
    }
}

__global__ __launch_bounds__(256) void scatter_ids_kernel(
    const int* __restrict__ ei, int E,
    int* __restrict__ cur_u, int* __restrict__ cur_i,
    int* __restrict__ eu_list, int* __restrict__ ei_list)
{
    int e = blockIdx.x * 256 + threadIdx.x;
    if (e < E) {
        int pu = atomicAdd(&cur_u[ei[e]], 1);
        eu_list[pu] = e;
        int pi = atomicAdd(&cur_i[ei[E + e]], 1);
        ei_list[pi] = e;
    }
}

// ----------------------- gather_u: quarter-wave, all dots -------------------
__global__ __launch_bounds__(256) void gather_u_kernel(
    const float* __restrict__ fusedU,   // [U,256]: um_att | um_b
    const float* __restrict__ fusedI,   // [I,256]: im_att | im_b
    const float* __restrict__ last_item, const float* __restrict__ last_user,
    const float* __restrict__ pVui, const float* __restrict__ pKiu,
    const int* __restrict__ ei, int E,
    const int* __restrict__ off_u, const int* __restrict__ eu_list,
    float2* __restrict__ x24,
    float* __restrict__ hLu, float* __restrict__ hSu, int U, float inv_sqrt_d)
{
    const int wid  = (int)(((size_t)blockIdx.x * blockDim.x + threadIdx.x) >> 6);
    const int lane = threadIdx.x & 63;
    if (wid >= U) return;
    const int g = lane >> 4;   // edge group 0..3
    const int q = lane & 15;   // float4 slot within row (slots q and q+16)

    const float4* fu4 = (const float4*)(fusedU    + (size_t)wid * 256);
    const float4* li4 = (const float4*)(last_item + (size_t)wid * 128);
    const float4* lu4 = (const float4*)(last_user + (size_t)wid * 128);
    const float4 um0 = fu4[q],      um1 = fu4[q + 16];
    const float4 li0 = li4[q],      li1 = li4[q + 16];
    const float4 lu0 = lu4[q],      lu1 = lu4[q + 16];

    float4 a1l = make_float4(0.f,0.f,0.f,0.f), a1h = make_float4(0.f,0.f,0.f,0.f);
    float4 a3l = make_float4(0.f,0.f,0.f,0.f), a3h = make_float4(0.f,0.f,0.f,0.f);
    float s1 = 0.f, s3 = 0.f;
    const int e0 = off_u[wid], e1 = off_u[wid + 1];
    for (int e = e0 + g; e < e1; e += 4) {
        const int eid = eu_list[e];
        const int dst = ei[E + eid];
        const float4* fI = (const float4*)(fusedI + (size_t)dst * 256);
        const float* pvp = pVui + (size_t)eid * 128;
        const float* pkp = pKiu + (size_t)eid * 128;
        float4 ia0 = fI[q],      ia1 = fI[q + 16];
        float4 ib0 = fI[32 + q], ib1 = fI[48 + q];
        float4 pv0 = nt_load4(pvp + q * 4), pv1 = nt_load4(pvp + 64 + q * 4);
        float4 pk0 = nt_load4(pkp + q * 4), pk1 = nt_load4(pkp + 64 + q * 4);

        float p0 = dot4(um0, ia0) + dot4(um1, ia1);
        float p1 = dot4(um0, pv0) + dot4(um1, pv1);
        float p2 = dot4(ia0, pk0) + dot4(ia1, pk1);
        float q1 = p0 + p1;                     // -> x1 (user longterm)
        float q2 = p0 + p2;                     // -> x2 (item longterm)
        float q3 = dot4(li0, ia0) + dot4(li1, ia1);  // -> x3
        float q4 = dot4(lu0, ia0) + dot4(lu1, ia1);  // -> x4
#pragma unroll
        for (int o = 8; o > 0; o >>= 1) {
            q1 += __shfl_xor(q1, o);
            q2 += __shfl_xor(q2, o);
            q3 += __shfl_xor(q3, o);
            q4 += __shfl_xor(q4, o);
        }
        float x1 = __expf(q1 * inv_sqrt_d);
        float x2 = __expf(q2 * inv_sqrt_d);
        float x3 = __expf(q3 * inv_sqrt_d);
        float x4 = __expf(q4 * inv_sqrt_d);
        a1l.x += x1*(ib0.x+pk0.x); a1l.y += x1*(ib0.y+pk0.y);
        a1l.z += x1*(ib0.z+pk0.z); a1l.w += x1*(ib0.w+pk0.w);
        a1h.x += x1*(ib1.x+pk1.x); a1h.y += x1*(ib1.y+pk1.y);
        a1h.z += x1*(ib1.z+pk1.z); a1h.w += x1*(ib1.w+pk1.w);
        a3l.x += x3*(ia0.x+1.f);   a3l.y += x3*(ia0.y+1.f);
        a3l.z += x3*(ia0.z+1.f);   a3l.w += x3*(ia0.w+1.f);
        a3h.x += x3*(ia1.x+1.f);   a3h.y += x3*(ia1.y+1.f);
        a3h.z += x3*(ia1.z+1.f);   a3h.w += x3*(ia1.w+1.f);
        s1 += x1; s3 += x3;
        if (q == 0) x24[eid] = make_float2(x2, x4);
    }
    // reduce across the 4 edge groups (lanes with same q, different g)
#pragma unroll
    for (int o = 16; o <= 32; o <<= 1) {
        a1l.x += __shfl_xor(a1l.x, o); a1l.y += __shfl_xor(a1l.y, o);
        a1l.z += __shfl_xor(a1l.z, o); a1l.w += __shfl_xor(a1l.w, o);
        a1h.x += __shfl_xor(a1h.x, o); a1h.y += __shfl_xor(a1h.y, o);
        a1h.z += __shfl_xor(a1h.z, o); a1h.w += __shfl_xor(a1h.w, o);
        a3l.x += __shfl_xor(a3l.x, o); a3l.y += __shfl_xor(a3l.y, o);
        a3l.z += __shfl_xor(a3l.z, o); a3l.w += __shfl_xor(a3l.w, o);
        a3h.x += __shfl_xor(a3h.x, o); a3h.y += __shfl_xor(a3h.y, o);
        a3h.z += __shfl_xor(a3h.z, o); a3h.w += __shfl_xor(a3h.w, o);
        s1 += __shfl_xor(s1, o);       s3 += __shfl_xor(s3, o);
    }
    if (lane < 16) {
        float r1 = (s1 > 0.f) ? 1.f / s1 : 0.f;
        float r3 = (s3 > 0.f) ? 1.f / s3 : 0.f;
        float4* oL = (float4*)(hLu + (size_t)wid * 128);
        float4* oS = (float4*)(hSu + (size_t)wid * 128);
        oL[q]      = make_float4(a1l.x*r1, a1l.y*r1, a1l.z*r1, a1l.w*r1);
        oL[q + 16] = make_float4(a1h.x*r1, a1h.y*r1, a1h.z*r1, a1h.w*r1);
        oS[q]      = make_float4(a3l.x*r3, a3l.y*r3, a3l.z*r3, a3l.w*r3);
        oS[q + 16] = make_float4(a3h.x*r3, a3h.y*r3, a3h.z*r3, a3h.w*r3);
    }
}

// ----------------------- gather_i: quarter-wave streaming accumulate --------
__global__ __launch_bounds__(256) void gather_i_kernel(
    const float* __restrict__ fusedU,   // [U,256]: um_att | um_b
    const float* __restrict__ pVui,
    const int* __restrict__ ei, int E,
    const int* __restrict__ off_i, const int* __restrict__ ei_list,
    const float2* __restrict__ x24,
    float* __restrict__ hLi, float* __restrict__ hSi, int I)
{
    const int wid  = (int)(((size_t)blockIdx.x * blockDim.x + threadIdx.x) >> 6);
    const int lane = threadIdx.x & 63;
    if (wid >= I) return;
    const int g = lane >> 4;
    const int q = lane & 15;

    float4 a2l = make_float4(0.f,0.f,0.f,0.f), a2h = make_float4(0.f,0.f,0.f,0.f);
    float4 a4l = make_float4(0.f,0.f,0.f,0.f), a4h = make_float4(0.f,0.f,0.f,0.f);
    float s2 = 0.f, s4 = 0.f;
    const int e0 = off_i[wid], e1 = off_i[wid + 1];
    for (int e = e0 + g; e < e1; e += 4) {
        const int eid = ei_list[e];
        const int src = ei[eid];
        const float2 x = x24[eid];
        const float4* fU = (const float4*)(fusedU + (size_t)src * 256);
        const float* pvp = pVui + (size_t)eid * 128;
        float4 ua0 = fU[q],      ua1 = fU[q + 16];
        float4 ub0 = fU[32 + q], ub1 = fU[48 + q];
        float4 pv0 = nt_load4(pvp + q * 4), pv1 = nt_load4(pvp + 64 + q * 4);
        a2l.x += x.x*(ub0.x+pv0.x); a2l.y += x.x*(ub0.y+pv0.y);
        a2l.z += x.x*(ub0.z+pv0.z); a2l.w += x.x*(ub0.w+pv0.w);
        a2h.x += x.x*(ub1.x+pv1.x); a2h.y += x.x*(ub1.y+pv1.y);
        a2h.z += x.x*(ub1.z+pv1.z); a2h.w += x.x*(ub1.w+pv1.w);
        a4l.x += x.y*(ua0.x+1.f);   a4l.y += x.y*(ua0.y+1.f);
        a4l.z += x.y*(ua0.z+1.f);   a4l.w += x.y*(ua0.w+1.f);
        a4h.x += x.y*(ua1.x+1.f);   a4h.y += x.y*(ua1.y+1.f);
        a4h.z += x.y*(ua1.z+1.f);   a4h.w += x.y*(ua1.w+1.f);
        s2 += x.x; s4 += x.y;
    }
#pragma unroll
    for (int o = 16; o <= 32; o <<= 1) {
        a2l.x += __shfl_xor(a2l.x, o); a2l.y += __shfl_xor(a2l.y, o);
        a2l.z += __shfl_xor(a2l.z, o); a2l.w += __shfl_xor(a2l.w, o);
        a2h.x += __shfl_xor(a2h.x, o); a2h.y += __shfl_xor(a2h.y, o);
        a2h.z += __shfl_xor(a2h.z, o); a2h.w += __shfl_xor(a2h.w, o);
        a4l.x += __shfl_xor(a4l.x, o); a4l.y += __shfl_xor(a4l.y, o);
        a4l.z += __shfl_xor(a4l.z, o); a4l.w += __shfl_xor(a4l.w, o);
        a4h.x += __shfl_xor(a4h.x, o); a4h.y += __shfl_xor(a4h.y, o);
        a4h.z += __shfl_xor(a4h.z, o); a4h.w += __shfl_xor(a4h.w, o);
        s2 += __shfl_xor(s2, o);       s4 += __shfl_xor(s4, o);
    }
    if (lane < 16) {
        float r2 = (s2 > 0.f) ? 1.f / s2 : 0.f;
        float r4 = (s4 > 0.f) ? 1.f / s4 : 0.f;
        float4* oL = (float4*)(hLi + (size_t)wid * 128);
        float4* oS = (float4*)(hSi + (size_t)wid * 128);
        oL[q]      = make_float4(a2l.x*r2, a2l.y*r2, a2l.z*r2, a2l.w*r2);
        oL[q + 16] = make_float4(a2h.x*r2, a2h.y*r2, a2h.z*r2, a2h.w*r2);
        oS[q]      = make_float4(a4l.x*r4, a4l.y*r4, a4l.z*r4, a4l.w*r4);
        oS[q + 16] = make_float4(a4h.x*r4, a4h.y*r4, a4h.z*r4, a4h.w*r4);
    }
}

// ---------------------------------------------------------------------------
extern "C" void kernel_launch(void* const* d_in, const int* in_sizes, int n_in,
                              void* d_out, int out_size, void* d_ws, size_t ws_size,
                              hipStream_t stream)
{
    const float* u_emb = (const float*)d_in[0];
    const float* i_emb = (const float*)d_in[1];
    const float* pVui  = (const float*)d_in[2];
    const float* pKiu  = (const float*)d_in[3];
    const float* w1    = (const float*)d_in[4];
    const float* w2    = (const float*)d_in[5];
    const float* w1b   = (const float*)d_in[6];
    const float* w2b   = (const float*)d_in[7];
    const float* w3    = (const float*)d_in[8];
    const float* w4    = (const float*)d_in[9];
    const int* edge_index = (const int*)d_in[10];
    const int* last_u     = (const int*)d_in[11];
    const int* last_i     = (const int*)d_in[12];

    const int U = in_sizes[0] / 128;
    const int I = in_sizes[1] / 128;
    const int E = in_sizes[10] / 2;
    const int nbu = (U + WB - 1) / WB;
    const int nbi = (I + WB - 1) / WB;

    float* ws = (float*)d_ws;
    float* fusedU    = ws;  ws += (size_t)U * 256;
    float* fusedI    = ws;  ws += (size_t)I * 256;
    float* last_item = ws;  ws += (size_t)U * 128;
    float* last_user = ws;  ws += (size_t)I * 128;
    float2* x24 = (float2*)ws;  ws += (size_t)E * 2;
    int* ip = (int*)ws;
    int* deg_u   = ip;  ip += U;
    int* deg_i   = ip;  ip += I;
    int* off_u   = ip;  ip += U + 1;
    int* off_i   = ip;  ip += I + 1;
    int* cur_u   = ip;  ip += U;
    int* cur_i   = ip;  ip += I;
    int* eu_list = ip;  ip += E;
    int* ei_list = ip;  ip += E;
    int* bsum    = ip;  ip += nbu + nbi;
    int* bscan   = ip;  ip += nbu + nbi;

    float* hLu = (float*)d_out;
    float* hSu = hLu + (size_t)U * 128;
    float* hLi = hSu + (size_t)U * 128;
    float* hSi = hLi + (size_t)I * 128;

    hipMemsetAsync(deg_u, 0, (size_t)(U + I) * sizeof(int), stream);

    dim3 blk(256);
    const int eblk = (E + 255) / 256;
    hist_kernel<<<eblk, blk, 0, stream>>>(edge_index, E, deg_u, deg_i);
    scan_blocksums_kernel<<<nbu + nbi, blk, 0, stream>>>(deg_u, U, nbu, deg_i, I, bsum);
    scan_partials_kernel<<<2, 64, 0, stream>>>(bsum, bscan, nbu, nbi, off_u, U, off_i, I);
    scan_final_kernel<<<nbu + nbi, blk, 0, stream>>>(
        deg_u, U, nbu, deg_i, I, bscan, off_u, cur_u, off_i, cur_i);
    scatter_ids_kernel<<<eblk, blk, 0, stream>>>(edge_index, E, cur_u, cur_i, eu_list, ei_list);

    Gemm6Desc gd;
    gd.X[0] = u_emb; gd.W[0] = w2;  gd.O[0] = fusedU;       gd.g[0] = nullptr;    gd.ostride[0] = 256; gd.nrows[0] = U;
    gd.X[1] = u_emb; gd.W[1] = w2b; gd.O[1] = fusedU + 128; gd.g[1] = nullptr;    gd.ostride[1] = 256; gd.nrows[1] = U;
    gd.X[2] = i_emb; gd.W[2] = w1;  gd.O[2] = fusedI;       gd.g[2] = nullptr;    gd.ostride[2] = 256; gd.nrows[2] = I;
    gd.X[3] = i_emb; gd.W[3] = w1b; gd.O[3] = fusedI + 128; gd.g[3] = nullptr;    gd.ostride[3] = 256; gd.nrows[3] = I;
    gd.X[4] = i_emb; gd.W[4] = w3;  gd.O[4] = last_item;    gd.g[4] = last_u + U; gd.ostride[4] = 128; gd.nrows[4] = U;
    gd.X[5] = u_emb; gd.W[5] = w4;  gd.O[5] = last_user;    gd.g[5] = last_i + I; gd.ostride[5] = 128; gd.nrows[5] = I;
    int maxrows = (U > I) ? U : I;
    dim3 ggrid((maxrows + 63) / 64, 6);
    gemm6_kernel<<<ggrid, blk, 0, stream>>>(gd);

    const float inv_sqrt_d = 1.0f / sqrtf(128.0f);
    gather_u_kernel<<<(U + 3) / 4, blk, 0, stream>>>(
        fusedU, fusedI, last_item, last_user, pVui, pKiu, edge_index, E,
        off_u, eu_list, x24, hLu, hSu, U, inv_sqrt_d);
    gather_i_kernel<<<(I + 3) / 4, blk, 0, stream>>>(
        fusedU, pVui, edge_index, E, off_i, ei_list, x24, hLi, hSi, I);
}

// Round 6
// 838.450 us; speedup vs baseline: 1.4596x; 1.0251x over previous
//
#include <hip/hip_runtime.h>
#include <hip/hip_bf16.h>
#include <math.h>

// ---------------------------------------------------------------------------
// DGSR layer, MI355X. H = 128 fixed.
//   1. CSR build: histogram -> 3-kernel scan -> edge-id scatter of PACKED
//      int2 records (partner_node, eid)  [kills one dependent load]
//   2. gemm6: single fused launch of all 6 projections into
//      fusedU=[um_att|um_b], fusedI=[im_att|im_b], last_item, last_user
//   3. gather_u: one wave per user, quarter-wave (16 lanes) per edge,
//      UNROLL x2 (8 edges in flight) + record prefetch pipeline.
//      Computes all 5 logit dots, accumulates hLu/hSu, writes x24[eid].
//   4. gather_i: same structure, pure streaming accumulate (no dots).
// pKiu read once, pVui twice (floor). exp without max-subtraction
// (logits ~N(0,1.4)). No f32 atomics anywhere.
// ---------------------------------------------------------------------------

#define WB 1024  // elements per scan block

typedef float fvec4 __attribute__((ext_vector_type(4)));

__device__ __forceinline__ float4 nt_load4(const float* p) {
    fvec4 v = __builtin_nontemporal_load((const fvec4*)p);
    return make_float4(v.x, v.y, v.z, v.w);
}
__device__ __forceinline__ float dot4(float4 a, float4 b) {
    return a.x * b.x + a.y * b.y + a.z * b.z + a.w * b.w;
}

// ----------------------- fused 6x GEMM: O[r][c] = sum_k X[g(r)][k]*W[c][k] --
struct Gemm6Desc {
    const float* X[6];
    const float* W[6];
    float*       O[6];
    const int*   g[6];
    int          ostride[6];
    int          nrows[6];
};

__global__ __launch_bounds__(256) void gemm6_kernel(Gemm6Desc d)
{
    __shared__ float Xl[64 * 32];
    __shared__ float Wl[128 * 32];
    const int j6 = blockIdx.y;
    const float* __restrict__ X = d.X[j6];
    const float* __restrict__ W = d.W[j6];
    float* __restrict__ O       = d.O[j6];
    const int* __restrict__ gidx = d.g[j6];
    const int ostride = d.ostride[j6];
    const int nrows   = d.nrows[j6];

    const int t  = threadIdx.x;
    const int tx = t & 15;
    const int ty = t >> 4;
    const int brow = blockIdx.x * 64;
    if (brow >= nrows) return;

    float acc[4][8];
#pragma unroll
    for (int j = 0; j < 4; ++j)
#pragma unroll
        for (int i = 0; i < 8; ++i) acc[j][i] = 0.f;

    for (int k0 = 0; k0 < 128; k0 += 32) {
        __syncthreads();
#pragma unroll
        for (int u = 0; u < 2; ++u) {
            int idx4 = t + u * 256;
            int r  = idx4 >> 3;
            int k4 = idx4 & 7;
            int row = brow + r;
            float4 v = make_float4(0.f, 0.f, 0.f, 0.f);
            if (row < nrows) {
                int g = gidx ? gidx[row] : row;
                v = *(const float4*)(X + (size_t)g * 128 + k0 + k4 * 4);
            }
            int sw = k4 ^ ((r >> 3) & 7);
            *(float4*)(Xl + r * 32 + sw * 4) = v;
        }
#pragma unroll
        for (int u = 0; u < 4; ++u) {
            int idx4 = t + u * 256;
            int c  = idx4 >> 3;
            int k4 = idx4 & 7;
            float4 v = *(const float4*)(W + (size_t)c * 128 + k0 + k4 * 4);
            int sw = k4 ^ ((c >> 3) & 7);
            *(float4*)(Wl + c * 32 + sw * 4) = v;
        }
        __syncthreads();
#pragma unroll
        for (int k4 = 0; k4 < 8; ++k4) {
            float4 xv[4], wv[8];
#pragma unroll
            for (int j = 0; j < 4; ++j) {
                int r = ty * 4 + j;
                xv[j] = *(const float4*)(Xl + r * 32 + ((k4 ^ ((r >> 3) & 7)) * 4));
            }
#pragma unroll
            for (int i = 0; i < 8; ++i) {
                int c = tx * 8 + i;
                wv[i] = *(const float4*)(Wl + c * 32 + ((k4 ^ ((c >> 3) & 7)) * 4));
            }
#pragma unroll
            for (int j = 0; j < 4; ++j)
#pragma unroll
                for (int i = 0; i < 8; ++i) {
                    acc[j][i] += xv[j].x * wv[i].x;
                    acc[j][i] += xv[j].y * wv[i].y;
                    acc[j][i] += xv[j].z * wv[i].z;
                    acc[j][i] += xv[j].w * wv[i].w;
                }
        }
    }
#pragma unroll
    for (int j = 0; j < 4; ++j) {
        int row = brow + ty * 4 + j;
        if (row < nrows) {
            float* op = O + (size_t)row * ostride + tx * 8;
            *(float4*)(op)     = make_float4(acc[j][0], acc[j][1], acc[j][2], acc[j][3]);
            *(float4*)(op + 4) = make_float4(acc[j][4], acc[j][5], acc[j][6], acc[j][7]);
        }
    }
}

// ----------------------- CSR build ------------------------------------------
__global__ __launch_bounds__(256) void hist_kernel(
    const int* __restrict__ ei, int E,
    int* __restrict__ deg_u, int* __restrict__ deg_i)
{
    int e = blockIdx.x * 256 + threadIdx.x;
    if (e < E) {
        atomicAdd(&deg_u[ei[e]], 1);
        atomicAdd(&deg_i[ei[E + e]], 1);
    }
}

__global__ __launch_bounds__(256) void scan_blocksums_kernel(
    const int* __restrict__ deg_u, int nu, int nbu,
    const int* __restrict__ deg_i, int ni,
    int* __restrict__ bsum)
{
    int b = blockIdx.x;
    const int* deg; int n; int base;
    if (b < nbu) { deg = deg_u; n = nu; base = b * WB; }
    else         { deg = deg_i; n = ni; base = (b - nbu) * WB; }
    int t = threadIdx.x;
    int s = 0;
#pragma unroll
    for (int j = 0; j < 4; ++j) {
        int i = base + t * 4 + j;
        if (i < n) s += deg[i];
    }
#pragma unroll
    for (int o = 32; o > 0; o >>= 1) s += __shfl_xor(s, o);
    __shared__ int wt[4];
    if ((t & 63) == 0) wt[t >> 6] = s;
    __syncthreads();
    if (t == 0) bsum[b] = wt[0] + wt[1] + wt[2] + wt[3];
}

__global__ void scan_partials_kernel(
    const int* __restrict__ bsum, int* __restrict__ bscan,
    int nbu, int nbi,
    int* __restrict__ off_u, int nu, int* __restrict__ off_i, int ni)
{
    if (threadIdx.x != 0) return;
    if (blockIdx.x == 0) {
        int c = 0;
        for (int b = 0; b < nbu; ++b) { bscan[b] = c; c += bsum[b]; }
        off_u[nu] = c;
    } else {
        int c = 0;
        for (int b = 0; b < nbi; ++b) { bscan[nbu + b] = c; c += bsum[nbu + b]; }
        off_i[ni] = c;
    }
}

__global__ __launch_bounds__(256) void scan_final_kernel(
    const int* __restrict__ deg_u, int nu, int nbu,
    const int* __restrict__ deg_i, int ni,
    const int* __restrict__ bscan,
    int* __restrict__ off_u, int* __restrict__ cur_u,
    int* __restrict__ off_i, int* __restrict__ cur_i)
{
    int b = blockIdx.x;
    const int* deg; int n; int base; int* off; int* cur;
    if (b < nbu) { deg = deg_u; n = nu; base = b * WB; off = off_u; cur = cur_u; }
    else         { deg = deg_i; n = ni; base = (b - nbu) * WB; off = off_i; cur = cur_i; }
    int t = threadIdx.x;
    int lane = t & 63, w = t >> 6;
    int v[4];
    int s = 0;
#pragma unroll
    for (int j = 0; j < 4; ++j) {
        int i = base + t * 4 + j;
        v[j] = (i < n) ? deg[i] : 0;
        s += v[j];
    }
    int inc = s;
#pragma unroll
    for (int o = 1; o < 64; o <<= 1) {
        int x = __shfl_up(inc, o);
        if (lane >= o) inc += x;
    }
    int excl = inc - s;
    __shared__ int wt[4];
    if (lane == 63) wt[w] = inc;
    __syncthreads();
    int wbase = 0;
    for (int j = 0; j < w; ++j) wbase += wt[j];
    int e = bscan[b] + wbase + excl;
#pragma unroll
    for (int j = 0; j < 4; ++j) {
        int i = base + t * 4 + j;
        if (i < n) { off[i] = e; cur[i] = e; }
        e += v[j];
    }
}

__global__ __launch_bounds__(256) void scatter_ids_kernel(
    const int* __restrict__ ei, int E,
    int* __restrict__ cur_u, int* __restrict__ cur_i,
    int2* __restrict__ eu_list, int2* __restrict__ ei_list)
{
    int e = blockIdx.x * 256 + threadIdx.x;
    if (e < E) {
        int u = ei[e], v = ei[E + e];
        int pu = atomicAdd(&cur_u[u], 1);
        eu_list[pu] = make_int2(v, e);   // (item, eid)
        int pi = atomicAdd(&cur_i[v], 1);
        ei_list[pi] = make_int2(u, e);   // (user, eid)
    }
}

// ----------------------- gather_u: quarter-wave, unroll x2, prefetch --------
__global__ __launch_bounds__(256) void gather_u_kernel(
    const float* __restrict__ fusedU,   // [U,256]: um_att | um_b
    const float* __restrict__ fusedI,   // [I,256]: im_att | im_b
    const float* __restrict__ last_item, const float* __restrict__ last_user,
    const float* __restrict__ pVui, const float* __restrict__ pKiu,
    const int2* __restrict__ lst,
    const int* __restrict__ off_u,
    float2* __restrict__ x24,
    float* __restrict__ hLu, float* __restrict__ hSu, int U, float inv_sqrt_d)
{
    const int wid  = (int)(((size_t)blockIdx.x * blockDim.x + threadIdx.x) >> 6);
    const int lane = threadIdx.x & 63;
    if (wid >= U) return;
    const int g = lane >> 4;   // edge group 0..3
    const int q = lane & 15;   // float4 slot within row

    const float4* fu4 = (const float4*)(fusedU    + (size_t)wid * 256);
    const float4* li4 = (const float4*)(last_item + (size_t)wid * 128);
    const float4* lu4 = (const float4*)(last_user + (size_t)wid * 128);
    const float4 um0 = fu4[q],      um1 = fu4[q + 16];
    const float4 li0 = li4[q],      li1 = li4[q + 16];
    const float4 lu0 = lu4[q],      lu1 = lu4[q + 16];

    float4 a1l = make_float4(0.f,0.f,0.f,0.f), a1h = make_float4(0.f,0.f,0.f,0.f);
    float4 a3l = make_float4(0.f,0.f,0.f,0.f), a3h = make_float4(0.f,0.f,0.f,0.f);
    float s1 = 0.f, s3 = 0.f;
    const int e0 = off_u[wid], e1 = off_u[wid + 1];

    int eA = e0 + g, eB = eA + 4;
    bool vA = eA < e1, vB = eB < e1;
    int2 rA = vA ? lst[eA] : make_int2(0, 0);
    int2 rB = vB ? lst[eB] : rA;

    while (vA) {
        // prefetch next pair of records
        int eA2 = eA + 8, eB2 = eB + 8;
        bool vA2 = eA2 < e1, vB2 = eB2 < e1;
        int2 rA2 = vA2 ? lst[eA2] : make_int2(0, 0);
        int2 rB2 = vB2 ? lst[eB2] : rA2;

        // batched row loads for A and B
        const float4* fIA = (const float4*)(fusedI + (size_t)rA.x * 256);
        const float*  pvA = pVui + (size_t)rA.y * 128;
        const float*  pkA = pKiu + (size_t)rA.y * 128;
        const float4* fIB = (const float4*)(fusedI + (size_t)rB.x * 256);
        const float*  pvB = pVui + (size_t)rB.y * 128;
        const float*  pkB = pKiu + (size_t)rB.y * 128;

        float4 iaA0 = fIA[q],      iaA1 = fIA[q + 16];
        float4 ibA0 = fIA[32 + q], ibA1 = fIA[48 + q];
        float4 pvA0 = nt_load4(pvA + q * 4), pvA1 = nt_load4(pvA + 64 + q * 4);
        float4 pkA0 = nt_load4(pkA + q * 4), pkA1 = nt_load4(pkA + 64 + q * 4);
        float4 iaB0 = fIB[q],      iaB1 = fIB[q + 16];
        float4 ibB0 = fIB[32 + q], ibB1 = fIB[48 + q];
        float4 pvB0 = nt_load4(pvB + q * 4), pvB1 = nt_load4(pvB + 64 + q * 4);
        float4 pkB0 = nt_load4(pkB + q * 4), pkB1 = nt_load4(pkB + 64 + q * 4);

        float pA0 = dot4(um0, iaA0) + dot4(um1, iaA1);
        float qA1 = pA0 + dot4(um0, pvA0) + dot4(um1, pvA1);
        float qA2 = pA0 + dot4(iaA0, pkA0) + dot4(iaA1, pkA1);
        float qA3 = dot4(li0, iaA0) + dot4(li1, iaA1);
        float qA4 = dot4(lu0, iaA0) + dot4(lu1, iaA1);
        float pB0 = dot4(um0, iaB0) + dot4(um1, iaB1);
        float qB1 = pB0 + dot4(um0, pvB0) + dot4(um1, pvB1);
        float qB2 = pB0 + dot4(iaB0, pkB0) + dot4(iaB1, pkB1);
        float qB3 = dot4(li0, iaB0) + dot4(li1, iaB1);
        float qB4 = dot4(lu0, iaB0) + dot4(lu1, iaB1);
#pragma unroll
        for (int o = 8; o > 0; o >>= 1) {
            qA1 += __shfl_xor(qA1, o); qA2 += __shfl_xor(qA2, o);
            qA3 += __shfl_xor(qA3, o); qA4 += __shfl_xor(qA4, o);
            qB1 += __shfl_xor(qB1, o); qB2 += __shfl_xor(qB2, o);
            qB3 += __shfl_xor(qB3, o); qB4 += __shfl_xor(qB4, o);
        }
        float x1A = __expf(qA1 * inv_sqrt_d);
        float x2A = __expf(qA2 * inv_sqrt_d);
        float x3A = __expf(qA3 * inv_sqrt_d);
        float x4A = __expf(qA4 * inv_sqrt_d);
        float mB  = vB ? 1.f : 0.f;
        float x1B = __expf(qB1 * inv_sqrt_d) * mB;
        float x2B = __expf(qB2 * inv_sqrt_d);
        float x3B = __expf(qB3 * inv_sqrt_d) * mB;
        float x4B = __expf(qB4 * inv_sqrt_d);

        a1l.x += x1A*(ibA0.x+pkA0.x) + x1B*(ibB0.x+pkB0.x);
        a1l.y += x1A*(ibA0.y+pkA0.y) + x1B*(ibB0.y+pkB0.y);
        a1l.z += x1A*(ibA0.z+pkA0.z) + x1B*(ibB0.z+pkB0.z);
        a1l.w += x1A*(ibA0.w+pkA0.w) + x1B*(ibB0.w+pkB0.w);
        a1h.x += x1A*(ibA1.x+pkA1.x) + x1B*(ibB1.x+pkB1.x);
        a1h.y += x1A*(ibA1.y+pkA1.y) + x1B*(ibB1.y+pkB1.y);
        a1h.z += x1A*(ibA1.z+pkA1.z) + x1B*(ibB1.z+pkB1.z);
        a1h.w += x1A*(ibA1.w+pkA1.w) + x1B*(ibB1.w+pkB1.w);
        a3l.x += x3A*(iaA0.x+1.f) + x3B*(iaB0.x+1.f);
        a3l.y += x3A*(iaA0.y+1.f) + x3B*(iaB0.y+1.f);
        a3l.z += x3A*(iaA0.z+1.f) + x3B*(iaB0.z+1.f);
        a3l.w += x3A*(iaA0.w+1.f) + x3B*(iaB0.w+1.f);
        a3h.x += x3A*(iaA1.x+1.f) + x3B*(iaB1.x+1.f);
        a3h.y += x3A*(iaA1.y+1.f) + x3B*(iaB1.y+1.f);
        a3h.z += x3A*(iaA1.z+1.f) + x3B*(iaB1.z+1.f);
        a3h.w += x3A*(iaA1.w+1.f) + x3B*(iaB1.w+1.f);
        s1 += x1A + x1B; s3 += x3A + x3B;
        if (q == 0) {
            x24[rA.y] = make_float2(x2A, x4A);
            if (vB) x24[rB.y] = make_float2(x2B, x4B);
        }
        eA = eA2; eB = eB2; vA = vA2; vB = vB2; rA = rA2; rB = rB2;
    }
    // reduce across the 4 edge groups
#pragma unroll
    for (int o = 16; o <= 32; o <<= 1) {
        a1l.x += __shfl_xor(a1l.x, o); a1l.y += __shfl_xor(a1l.y, o);
        a1l.z += __shfl_xor(a1l.z, o); a1l.w += __shfl_xor(a1l.w, o);
        a1h.x += __shfl_xor(a1h.x, o); a1h.y += __shfl_xor(a1h.y, o);
        a1h.z += __shfl_xor(a1h.z, o); a1h.w += __shfl_xor(a1h.w, o);
        a3l.x += __shfl_xor(a3l.x, o); a3l.y += __shfl_xor(a3l.y, o);
        a3l.z += __shfl_xor(a3l.z, o); a3l.w += __shfl_xor(a3l.w, o);
        a3h.x += __shfl_xor(a3h.x, o); a3h.y += __shfl_xor(a3h.y, o);
        a3h.z += __shfl_xor(a3h.z, o); a3h.w += __shfl_xor(a3h.w, o);
        s1 += __shfl_xor(s1, o);       s3 += __shfl_xor(s3, o);
    }
    if (lane < 16) {
        float r1 = (s1 > 0.f) ? 1.f / s1 : 0.f;
        float r3 = (s3 > 0.f) ? 1.f / s3 : 0.f;
        float4* oL = (float4*)(hLu + (size_t)wid * 128);
        float4* oS = (float4*)(hSu + (size_t)wid * 128);
        oL[q]      = make_float4(a1l.x*r1, a1l.y*r1, a1l.z*r1, a1l.w*r1);
        oL[q + 16] = make_float4(a1h.x*r1, a1h.y*r1, a1h.z*r1, a1h.w*r1);
        oS[q]      = make_float4(a3l.x*r3, a3l.y*r3, a3l.z*r3, a3l.w*r3);
        oS[q + 16] = make_float4(a3h.x*r3, a3h.y*r3, a3h.z*r3, a3h.w*r3);
    }
}

// ----------------------- gather_i: quarter-wave, unroll x2, prefetch --------
__global__ __launch_bounds__(256) void gather_i_kernel(
    const float* __restrict__ fusedU,   // [U,256]: um_att | um_b
    const float* __restrict__ pVui,
    const int2* __restrict__ lst,
    const int* __restrict__ off_i,
    const float2* __restrict__ x24,
    float* __restrict__ hLi, float* __restrict__ hSi, int I)
{
    const int wid  = (int)(((size_t)blockIdx.x * blockDim.x + threadIdx.x) >> 6);
    const int lane = threadIdx.x & 63;
    if (wid >= I) return;
    const int g = lane >> 4;
    const int q = lane & 15;

    float4 a2l = make_float4(0.f,0.f,0.f,0.f), a2h = make_float4(0.f,0.f,0.f,0.f);
    float4 a4l = make_float4(0.f,0.f,0.f,0.f), a4h = make_float4(0.f,0.f,0.f,0.f);
    float s2 = 0.f, s4 = 0.f;
    const int e0 = off_i[wid], e1 = off_i[wid + 1];

    int eA = e0 + g, eB = eA + 4;
    bool vA = eA < e1, vB = eB < e1;
    int2 rA = vA ? lst[eA] : make_int2(0, 0);
    int2 rB = vB ? lst[eB] : rA;

    while (vA) {
        int eA2 = eA + 8, eB2 = eB + 8;
        bool vA2 = eA2 < e1, vB2 = eB2 < e1;
        int2 rA2 = vA2 ? lst[eA2] : make_int2(0, 0);
        int2 rB2 = vB2 ? lst[eB2] : rA2;

        const float4* fUA = (const float4*)(fusedU + (size_t)rA.x * 256);
        const float*  pvA = pVui + (size_t)rA.y * 128;
        const float4* fUB = (const float4*)(fusedU + (size_t)rB.x * 256);
        const float*  pvB = pVui + (size_t)rB.y * 128;

        float2 xA = x24[rA.y];
        float2 xB = x24[rB.y];
        float4 uaA0 = fUA[q],      uaA1 = fUA[q + 16];
        float4 ubA0 = fUA[32 + q], ubA1 = fUA[48 + q];
        float4 pvA0 = nt_load4(pvA + q * 4), pvA1 = nt_load4(pvA + 64 + q * 4);
        float4 uaB0 = fUB[q],      uaB1 = fUB[q + 16];
        float4 ubB0 = fUB[32 + q], ubB1 = fUB[48 + q];
        float4 pvB0 = nt_load4(pvB + q * 4), pvB1 = nt_load4(pvB + 64 + q * 4);

        if (!vB) { xB.x = 0.f; xB.y = 0.f; }
        a2l.x += xA.x*(ubA0.x+pvA0.x) + xB.x*(ubB0.x+pvB0.x);
        a2l.y += xA.x*(ubA0.y+pvA0.y) + xB.x*(ubB0.y+pvB0.y);
        a2l.z += xA.x*(ubA0.z+pvA0.z) + xB.x*(ubB0.z+pvB0.z);
        a2l.w += xA.x*(ubA0.w+pvA0.w) + xB.x*(ubB0.w+pvB0.w);
        a2h.x += xA.x*(ubA1.x+pvA1.x) + xB.x*(ubB1.x+pvB1.x);
        a2h.y += xA.x*(ubA1.y+pvA1.y) + xB.x*(ubB1.y+pvB1.y);
        a2h.z += xA.x*(ubA1.z+pvA1.z) + xB.x*(ubB1.z+pvB1.z);
        a2h.w += xA.x*(ubA1.w+pvA1.w) + xB.x*(ubB1.w+pvB1.w);
        a4l.x += xA.y*(uaA0.x+1.f) + xB.y*(uaB0.x+1.f);
        a4l.y += xA.y*(uaA0.y+1.f) + xB.y*(uaB0.y+1.f);
        a4l.z += xA.y*(uaA0.z+1.f) + xB.y*(uaB0.z+1.f);
        a4l.w += xA.y*(uaA0.w+1.f) + xB.y*(uaB0.w+1.f);
        a4h.x += xA.y*(uaA1.x+1.f) + xB.y*(uaB1.x+1.f);
        a4h.y += xA.y*(uaA1.y+1.f) + xB.y*(uaB1.y+1.f);
        a4h.z += xA.y*(uaA1.z+1.f) + xB.y*(uaB1.z+1.f);
        a4h.w += xA.y*(uaA1.w+1.f) + xB.y*(uaB1.w+1.f);
        s2 += xA.x + xB.x; s4 += xA.y + xB.y;

        eA = eA2; eB = eB2; vA = vA2; vB = vB2; rA = rA2; rB = rB2;
    }
#pragma unroll
    for (int o = 16; o <= 32; o <<= 1) {
        a2l.x += __shfl_xor(a2l.x, o); a2l.y += __shfl_xor(a2l.y, o);
        a2l.z += __shfl_xor(a2l.z, o); a2l.w += __shfl_xor(a2l.w, o);
        a2h.x += __shfl_xor(a2h.x, o); a2h.y += __shfl_xor(a2h.y, o);
        a2h.z += __shfl_xor(a2h.z, o); a2h.w += __shfl_xor(a2h.w, o);
        a4l.x += __shfl_xor(a4l.x, o); a4l.y += __shfl_xor(a4l.y, o);
        a4l.z += __shfl_xor(a4l.z, o); a4l.w += __shfl_xor(a4l.w, o);
        a4h.x += __shfl_xor(a4h.x, o); a4h.y += __shfl_xor(a4h.y, o);
        a4h.z += __shfl_xor(a4h.w - a4h.w + a4h.z, o); a4h.w += __shfl_xor(a4h.w, o);
        s2 += __shfl_xor(s2, o);       s4 += __shfl_xor(s4, o);
    }
    if (lane < 16) {
        float r2 = (s2 > 0.f) ? 1.f / s2 : 0.f;
        float r4 = (s4 > 0.f) ? 1.f / s4 : 0.f;
        float4* oL = (float4*)(hLi + (size_t)wid * 128);
        float4* oS = (float4*)(hSi + (size_t)wid * 128);
        oL[q]      = make_float4(a2l.x*r2, a2l.y*r2, a2l.z*r2, a2l.w*r2);
        oL[q + 16] = make_float4(a2h.x*r2, a2h.y*r2, a2h.z*r2, a2h.w*r2);
        oS[q]      = make_float4(a4l.x*r4, a4l.y*r4, a4l.z*r4, a4l.w*r4);
        oS[q + 16] = make_float4(a4h.x*r4, a4h.y*r4, a4h.z*r4, a4h.w*r4);
    }
}

// ---------------------------------------------------------------------------
extern "C" void kernel_launch(void* const* d_in, const int* in_sizes, int n_in,
                              void* d_out, int out_size, void* d_ws, size_t ws_size,
                              hipStream_t stream)
{
    const float* u_emb = (const float*)d_in[0];
    const float* i_emb = (const float*)d_in[1];
    const float* pVui  = (const float*)d_in[2];
    const float* pKiu  = (const float*)d_in[3];
    const float* w1    = (const float*)d_in[4];
    const float* w2    = (const float*)d_in[5];
    const float* w1b   = (const float*)d_in[6];
    const float* w2b   = (const float*)d_in[7];
    const float* w3    = (const float*)d_in[8];
    const float* w4    = (const float*)d_in[9];
    const int* edge_index = (const int*)d_in[10];
    const int* last_u     = (const int*)d_in[11];
    const int* last_i     = (const int*)d_in[12];

    const int U = in_sizes[0] / 128;
    const int I = in_sizes[1] / 128;
    const int E = in_sizes[10] / 2;
    const int nbu = (U + WB - 1) / WB;
    const int nbi = (I + WB - 1) / WB;

    float* ws = (float*)d_ws;
    float* fusedU    = ws;  ws += (size_t)U * 256;
    float* fusedI    = ws;  ws += (size_t)I * 256;
    float* last_item = ws;  ws += (size_t)U * 128;
    float* last_user = ws;  ws += (size_t)I * 128;
    float2* x24 = (float2*)ws;  ws += (size_t)E * 2;
    int2* eu_list = (int2*)ws;  ws += (size_t)E * 2;
    int2* ei_list = (int2*)ws;  ws += (size_t)E * 2;
    int* ip = (int*)ws;
    int* deg_u   = ip;  ip += U;
    int* deg_i   = ip;  ip += I;
    int* off_u   = ip;  ip += U + 1;
    int* off_i   = ip;  ip += I + 1;
    int* cur_u   = ip;  ip += U;
    int* cur_i   = ip;  ip += I;
    int* bsum    = ip;  ip += nbu + nbi;
    int* bscan   = ip;  ip += nbu + nbi;

    float* hLu = (float*)d_out;
    float* hSu = hLu + (size_t)U * 128;
    float* hLi = hSu + (size_t)U * 128;
    float* hSi = hLi + (size_t)I * 128;

    hipMemsetAsync(deg_u, 0, (size_t)(U + I) * sizeof(int), stream);

    dim3 blk(256);
    const int eblk = (E + 255) / 256;
    hist_kernel<<<eblk, blk, 0, stream>>>(edge_index, E, deg_u, deg_i);
    scan_blocksums_kernel<<<nbu + nbi, blk, 0, stream>>>(deg_u, U, nbu, deg_i, I, bsum);
    scan_partials_kernel<<<2, 64, 0, stream>>>(bsum, bscan, nbu, nbi, off_u, U, off_i, I);
    scan_final_kernel<<<nbu + nbi, blk, 0, stream>>>(
        deg_u, U, nbu, deg_i, I, bscan, off_u, cur_u, off_i, cur_i);
    scatter_ids_kernel<<<eblk, blk, 0, stream>>>(edge_index, E, cur_u, cur_i, eu_list, ei_list);

    Gemm6Desc gd;
    gd.X[0] = u_emb; gd.W[0] = w2;  gd.O[0] = fusedU;       gd.g[0] = nullptr;    gd.ostride[0] = 256; gd.nrows[0] = U;
    gd.X[1] = u_emb; gd.W[1] = w2b; gd.O[1] = fusedU + 128; gd.g[1] = nullptr;    gd.ostride[1] = 256; gd.nrows[1] = U;
    gd.X[2] = i_emb; gd.W[2] = w1;  gd.O[2] = fusedI;       gd.g[2] = nullptr;    gd.ostride[2] = 256; gd.nrows[2] = I;
    gd.X[3] = i_emb; gd.W[3] = w1b; gd.O[3] = fusedI + 128; gd.g[3] = nullptr;    gd.ostride[3] = 256; gd.nrows[3] = I;
    gd.X[4] = i_emb; gd.W[4] = w3;  gd.O[4] = last_item;    gd.g[4] = last_u + U; gd.ostride[4] = 128; gd.nrows[4] = U;
    gd.X[5] = u_emb; gd.W[5] = w4;  gd.O[5] = last_user;    gd.g[5] = last_i + I; gd.ostride[5] = 128; gd.nrows[5] = I;
    int maxrows = (U > I) ? U : I;
    dim3 ggrid((maxrows + 63) / 64, 6);
    gemm6_kernel<<<ggrid, blk, 0, stream>>>(gd);

    const float inv_sqrt_d = 1.0f / sqrtf(128.0f);
    gather_u_kernel<<<(U + 3) / 4, blk, 0, stream>>>(
        fusedU, fusedI, last_item, last_user, pVui, pKiu, eu_list,
        off_u, x24, hLu, hSu, U, inv_sqrt_d);
    gather_i_kernel<<<(I + 3) / 4, blk, 0, stream>>>(
        fusedU, pVui, ei_list, off_i, x24, hLi, hSi, I);
}